// Round 1
// baseline (1035.993 us; speedup 1.0000x reference)
//
#include <hip/hip_runtime.h>

constexpr int N_NODES = 100000;
constexpr int N_EDGES = 1000000;
constexpr int DIM = 64;

// Aggregate: 16 threads per edge; each thread loads a float4 of x[src] and
// atomic-adds 4 floats into accum[tgt]. Lane 0 of each edge-group bumps deg.
__global__ __launch_bounds__(256) void agg_kernel(
    const float* __restrict__ x,
    const int* __restrict__ eidx,   // [0,E) = targets i, [E,2E) = sources j
    float* __restrict__ accum,
    float* __restrict__ deg)
{
    unsigned t = blockIdx.x * 256u + threadIdx.x;
    unsigned e = t >> 4;
    unsigned lane = t & 15u;
    if (e >= (unsigned)N_EDGES) return;
    int i = eidx[e];             // target node
    int j = eidx[N_EDGES + e];   // source node
    float4 v = ((const float4*)(x + (size_t)j * DIM))[lane];
    float* dst = accum + (size_t)i * DIM + lane * 4u;
    unsafeAtomicAdd(dst + 0, v.x);
    unsafeAtomicAdd(dst + 1, v.y);
    unsafeAtomicAdd(dst + 2, v.z);
    unsafeAtomicAdd(dst + 3, v.w);
    if (lane == 0) unsafeAtomicAdd(deg + i, 1.0f);
}

// Finalize: one thread per node. h = accum[n]/max(deg,1) held in 64 VGPRs,
// out[d] = (h . W[d][:]) + b[d], masked to 0 when deg==0.
// W indices are wave-uniform -> scalar loads feed SGPR-operand FMAs.
__global__ __launch_bounds__(256) void finalize_kernel(
    const float* __restrict__ accum,
    const float* __restrict__ deg,
    const float* __restrict__ W,    // (OUT, IN) row-major
    const float* __restrict__ b,
    float* __restrict__ out)
{
    int n = blockIdx.x * 256 + threadIdx.x;
    if (n >= N_NODES) return;
    float dg = deg[n];
    float inv = 1.0f / fmaxf(dg, 1.0f);
    float mask = dg > 0.0f ? 1.0f : 0.0f;

    float h[DIM];
    const float4* arow = (const float4*)(accum + (size_t)n * DIM);
#pragma unroll
    for (int k = 0; k < DIM / 4; ++k) {
        float4 v = arow[k];
        h[4 * k + 0] = v.x * inv;
        h[4 * k + 1] = v.y * inv;
        h[4 * k + 2] = v.z * inv;
        h[4 * k + 3] = v.w * inv;
    }

    float4* orow = (float4*)(out + (size_t)n * DIM);
#pragma unroll 1
    for (int d0 = 0; d0 < DIM; d0 += 4) {
        float acc0 = 0.f, acc1 = 0.f, acc2 = 0.f, acc3 = 0.f;
        const float* w0 = W + (size_t)(d0 + 0) * DIM;
        const float* w1 = W + (size_t)(d0 + 1) * DIM;
        const float* w2 = W + (size_t)(d0 + 2) * DIM;
        const float* w3 = W + (size_t)(d0 + 3) * DIM;
#pragma unroll
        for (int k = 0; k < DIM; ++k) {
            float hk = h[k];
            acc0 = fmaf(hk, w0[k], acc0);
            acc1 = fmaf(hk, w1[k], acc1);
            acc2 = fmaf(hk, w2[k], acc2);
            acc3 = fmaf(hk, w3[k], acc3);
        }
        float4 o;
        o.x = (acc0 + b[d0 + 0]) * mask;
        o.y = (acc1 + b[d0 + 1]) * mask;
        o.z = (acc2 + b[d0 + 2]) * mask;
        o.w = (acc3 + b[d0 + 3]) * mask;
        orow[d0 / 4] = o;
    }
}

extern "C" void kernel_launch(void* const* d_in, const int* in_sizes, int n_in,
                              void* d_out, int out_size, void* d_ws, size_t ws_size,
                              hipStream_t stream) {
    const float* x   = (const float*)d_in[0];   // (N, 64)
    const int*   ei  = (const int*)d_in[1];     // (2, E)
    const float* W   = (const float*)d_in[2];   // (64, 64)
    const float* b   = (const float*)d_in[3];   // (64,)
    float* out = (float*)d_out;                 // (N, 64)

    float* accum = (float*)d_ws;                       // N*64 floats
    float* deg   = accum + (size_t)N_NODES * DIM;      // N floats

    // ws is re-poisoned to 0xAA before every launch: zero what we use.
    hipMemsetAsync(d_ws, 0, ((size_t)N_NODES * DIM + N_NODES) * sizeof(float), stream);

    // E*16 threads / 256 = 62500 blocks exactly
    agg_kernel<<<(N_EDGES * 16) / 256, 256, 0, stream>>>(x, ei, accum, deg);
    finalize_kernel<<<(N_NODES + 255) / 256, 256, 0, stream>>>(accum, deg, W, b, out);
}

// Round 2
// 230.696 us; speedup vs baseline: 4.4907x; 4.4907x over previous
//
#include <hip/hip_runtime.h>

constexpr int N_NODES = 100000;
constexpr int N_EDGES = 1000000;
constexpr int DIM = 64;

constexpr int SCAN_BLK = 512;
constexpr int NBLK = (N_NODES + SCAN_BLK - 1) / SCAN_BLK;   // 196

// --- Phase 1: degree count + per-edge ticket (1M int atomics) ---------------
__global__ __launch_bounds__(256) void count_ticket(
    const int* __restrict__ eidx, int* __restrict__ deg, int* __restrict__ ticket)
{
    int e = blockIdx.x * 256 + threadIdx.x;
    if (e >= N_EDGES) return;
    int i = eidx[e];                       // target node
    ticket[e] = atomicAdd(&deg[i], 1);
}

// --- Phase 2: exclusive prefix scan of deg -> offsets -----------------------
__global__ __launch_bounds__(SCAN_BLK) void scan_block(
    const int* __restrict__ deg, int* __restrict__ offs, int* __restrict__ bsums)
{
    __shared__ int s[SCAN_BLK];
    int n = blockIdx.x * SCAN_BLK + threadIdx.x;
    int v = (n < N_NODES) ? deg[n] : 0;
    s[threadIdx.x] = v;
    __syncthreads();
    for (int d = 1; d < SCAN_BLK; d <<= 1) {
        int t = (threadIdx.x >= d) ? s[threadIdx.x - d] : 0;
        __syncthreads();
        s[threadIdx.x] += t;
        __syncthreads();
    }
    if (n < N_NODES) offs[n] = s[threadIdx.x] - v;          // exclusive within block
    if (threadIdx.x == SCAN_BLK - 1) bsums[blockIdx.x] = s[SCAN_BLK - 1];
}

__global__ __launch_bounds__(256) void scan_sums(int* __restrict__ bsums)
{
    __shared__ int s[256];
    int v = (threadIdx.x < NBLK) ? bsums[threadIdx.x] : 0;
    s[threadIdx.x] = v;
    __syncthreads();
    for (int d = 1; d < 256; d <<= 1) {
        int t = (threadIdx.x >= d) ? s[threadIdx.x - d] : 0;
        __syncthreads();
        s[threadIdx.x] += t;
        __syncthreads();
    }
    if (threadIdx.x < NBLK) bsums[threadIdx.x] = s[threadIdx.x] - v;  // exclusive
}

__global__ __launch_bounds__(SCAN_BLK) void add_base(
    int* __restrict__ offs, const int* __restrict__ bsums)
{
    int n = blockIdx.x * SCAN_BLK + threadIdx.x;
    if (n >= N_NODES) return;
    offs[n] += bsums[blockIdx.x];
}

// --- Phase 3: scatter edge sources into CSR buckets (no atomics) ------------
__global__ __launch_bounds__(256) void scatter_kernel(
    const int* __restrict__ eidx, const int* __restrict__ offs,
    const int* __restrict__ ticket, int* __restrict__ bucket)
{
    int e = blockIdx.x * 256 + threadIdx.x;
    if (e >= N_EDGES) return;
    int i = eidx[e];
    int j = eidx[N_EDGES + e];
    bucket[offs[i] + ticket[e]] = j;
}

// --- Phase 4: y = x @ W^T (no bias; folded into gather) ---------------------
// One thread per node; W row pointers are wave-uniform -> scalar loads.
__global__ __launch_bounds__(256) void transform_kernel(
    const float* __restrict__ x, const float* __restrict__ W, float* __restrict__ y)
{
    int n = blockIdx.x * 256 + threadIdx.x;
    if (n >= N_NODES) return;

    float h[DIM];
    const float4* xrow = (const float4*)(x + (size_t)n * DIM);
#pragma unroll
    for (int k = 0; k < DIM / 4; ++k) {
        float4 v = xrow[k];
        h[4 * k + 0] = v.x; h[4 * k + 1] = v.y; h[4 * k + 2] = v.z; h[4 * k + 3] = v.w;
    }

    float4* yrow = (float4*)(y + (size_t)n * DIM);
#pragma unroll 1
    for (int d0 = 0; d0 < DIM; d0 += 4) {
        float a0 = 0.f, a1 = 0.f, a2 = 0.f, a3 = 0.f;
        const float* w0 = W + (size_t)(d0 + 0) * DIM;
        const float* w1 = W + (size_t)(d0 + 1) * DIM;
        const float* w2 = W + (size_t)(d0 + 2) * DIM;
        const float* w3 = W + (size_t)(d0 + 3) * DIM;
#pragma unroll
        for (int k = 0; k < DIM; ++k) {
            float hk = h[k];
            a0 = fmaf(hk, w0[k], a0);
            a1 = fmaf(hk, w1[k], a1);
            a2 = fmaf(hk, w2[k], a2);
            a3 = fmaf(hk, w3[k], a3);
        }
        float4 o; o.x = a0; o.y = a1; o.z = a2; o.w = a3;
        yrow[d0 / 4] = o;
    }
}

// --- Phase 5: per-node gather-sum of y rows, divide by deg, add bias --------
// 16 threads per node; each lane owns one float4 (4 dims) of the row.
__global__ __launch_bounds__(256) void gather_kernel(
    const float* __restrict__ y, const int* __restrict__ offs,
    const int* __restrict__ deg, const int* __restrict__ bucket,
    const float* __restrict__ b, float* __restrict__ out)
{
    unsigned t = blockIdx.x * 256u + threadIdx.x;
    unsigned n = t >> 4;
    unsigned lane = t & 15u;
    if (n >= (unsigned)N_NODES) return;

    int start = offs[n];
    int d = deg[n];
    const float4* y4 = (const float4*)y;
    float4 acc = make_float4(0.f, 0.f, 0.f, 0.f);
    for (int e = 0; e < d; ++e) {
        int j = bucket[start + e];
        float4 v = y4[(size_t)j * (DIM / 4) + lane];
        acc.x += v.x; acc.y += v.y; acc.z += v.z; acc.w += v.w;
    }

    float4 o;
    if (d > 0) {
        float inv = 1.0f / (float)d;
        float4 bb = ((const float4*)b)[lane];
        o.x = acc.x * inv + bb.x;
        o.y = acc.y * inv + bb.y;
        o.z = acc.z * inv + bb.z;
        o.w = acc.w * inv + bb.w;
    } else {
        o = make_float4(0.f, 0.f, 0.f, 0.f);
    }
    ((float4*)out)[(size_t)n * (DIM / 4) + lane] = o;
}

extern "C" void kernel_launch(void* const* d_in, const int* in_sizes, int n_in,
                              void* d_out, int out_size, void* d_ws, size_t ws_size,
                              hipStream_t stream) {
    const float* x  = (const float*)d_in[0];   // (N, 64)
    const int*   ei = (const int*)d_in[1];     // (2, E): [0,E) targets, [E,2E) sources
    const float* W  = (const float*)d_in[2];   // (64, 64)
    const float* b  = (const float*)d_in[3];   // (64,)
    float* out = (float*)d_out;                // (N, 64)

    // Workspace layout (all 4-byte elems): total ~34.5 MB
    float* y      = (float*)d_ws;                        // N*64
    int*   deg    = (int*)(y + (size_t)N_NODES * DIM);   // N
    int*   offs   = deg + N_NODES;                       // N
    int*   ticket = offs + N_NODES;                      // E
    int*   bucket = ticket + N_EDGES;                    // E
    int*   bsums  = bucket + N_EDGES;                    // 256

    // Only deg needs zeroing (everything else is fully overwritten).
    hipMemsetAsync(deg, 0, N_NODES * sizeof(int), stream);

    count_ticket<<<(N_EDGES + 255) / 256, 256, 0, stream>>>(ei, deg, ticket);
    scan_block<<<NBLK, SCAN_BLK, 0, stream>>>(deg, offs, bsums);
    scan_sums<<<1, 256, 0, stream>>>(bsums);
    add_base<<<NBLK, SCAN_BLK, 0, stream>>>(offs, bsums);
    scatter_kernel<<<(N_EDGES + 255) / 256, 256, 0, stream>>>(ei, offs, ticket, bucket);
    transform_kernel<<<(N_NODES + 255) / 256, 256, 0, stream>>>(x, W, y);
    gather_kernel<<<(N_NODES * 16) / 256, 256, 0, stream>>>(y, offs, deg, bucket, b, out);
}

// Round 3
// 198.102 us; speedup vs baseline: 5.2296x; 1.1645x over previous
//
#include <hip/hip_runtime.h>

constexpr int N_NODES = 100000;
constexpr int N_EDGES = 1000000;
constexpr int DIM = 64;

constexpr int SCAN_BLK = 512;
constexpr int NBLK = (N_NODES + SCAN_BLK - 1) / SCAN_BLK;   // 196

constexpr int TILE = 64;    // nodes per fused block
constexpr int PAD = 65;     // LDS row stride (floats) — breaks bank conflicts

// --- Phase 1: degree count + per-edge ticket (1M int atomics) ---------------
__global__ __launch_bounds__(256) void count_ticket(
    const int* __restrict__ eidx, int* __restrict__ deg, int* __restrict__ ticket)
{
    int e = blockIdx.x * 256 + threadIdx.x;
    if (e >= N_EDGES) return;
    int i = eidx[e];                       // target node
    ticket[e] = atomicAdd(&deg[i], 1);
}

// --- Phase 2: exclusive prefix scan of deg -> offsets -----------------------
__global__ __launch_bounds__(SCAN_BLK) void scan_block(
    const int* __restrict__ deg, int* __restrict__ offs, int* __restrict__ bsums)
{
    __shared__ int s[SCAN_BLK];
    int n = blockIdx.x * SCAN_BLK + threadIdx.x;
    int v = (n < N_NODES) ? deg[n] : 0;
    s[threadIdx.x] = v;
    __syncthreads();
    for (int d = 1; d < SCAN_BLK; d <<= 1) {
        int t = (threadIdx.x >= d) ? s[threadIdx.x - d] : 0;
        __syncthreads();
        s[threadIdx.x] += t;
        __syncthreads();
    }
    if (n < N_NODES) offs[n] = s[threadIdx.x] - v;          // exclusive within block
    if (threadIdx.x == SCAN_BLK - 1) bsums[blockIdx.x] = s[SCAN_BLK - 1];
}

__global__ __launch_bounds__(256) void scan_sums(int* __restrict__ bsums)
{
    __shared__ int s[256];
    int v = (threadIdx.x < NBLK) ? bsums[threadIdx.x] : 0;
    s[threadIdx.x] = v;
    __syncthreads();
    for (int d = 1; d < 256; d <<= 1) {
        int t = (threadIdx.x >= d) ? s[threadIdx.x - d] : 0;
        __syncthreads();
        s[threadIdx.x] += t;
        __syncthreads();
    }
    if (threadIdx.x < NBLK) bsums[threadIdx.x] = s[threadIdx.x] - v;  // exclusive
}

__global__ __launch_bounds__(SCAN_BLK) void add_base(
    int* __restrict__ offs, const int* __restrict__ bsums)
{
    int n = blockIdx.x * SCAN_BLK + threadIdx.x;
    if (n >= N_NODES) return;
    offs[n] += bsums[blockIdx.x];
}

// --- Phase 3: scatter edge sources into CSR buckets (no atomics) ------------
__global__ __launch_bounds__(256) void scatter_kernel(
    const int* __restrict__ eidx, const int* __restrict__ offs,
    const int* __restrict__ ticket, int* __restrict__ bucket)
{
    int e = blockIdx.x * 256 + threadIdx.x;
    if (e >= N_EDGES) return;
    int i = eidx[e];
    int j = eidx[N_EDGES + e];
    bucket[offs[i] + ticket[e]] = j;
}

// --- Phase 4 (fused): gather mean of x rows per node + 64x64 matmul + bias --
// Block = 256 threads = 4 waves, one 64-node tile.
//   Gather: wave w handles nodes tile_base + w*16 + i; all 64 lanes of the
//           wave cooperate on one node (lane = feature dim k) -> each edge is
//           one fully-coalesced 256B read of x[j][0..63].
//   Matmul: thread t computes out[base + (t&63)][d0..d0+15], d0=(t>>6)*16.
//           agg from LDS (stride-65, conflict-free), W via uniform s_loads.
__global__ __launch_bounds__(256) void fused_gather_mm(
    const float* __restrict__ x, const int* __restrict__ offs,
    const int* __restrict__ deg, const int* __restrict__ bucket,
    const float* __restrict__ W, const float* __restrict__ b,
    float* __restrict__ out)
{
    __shared__ float tile[TILE * PAD];   // 16.6 KB

    const int base = blockIdx.x * TILE;
    const int lane = threadIdx.x & 63;
    const int wid  = threadIdx.x >> 6;   // 0..3

    // ---- gather: 16 nodes per wave ----
    for (int i = 0; i < 16; ++i) {
        int row = wid * 16 + i;
        int node = base + row;
        float sum = 0.0f;
        if (node < N_NODES) {
            int start = __builtin_amdgcn_readfirstlane(offs[node]);
            int d     = __builtin_amdgcn_readfirstlane(deg[node]);
            int e = 0;
            for (; e + 4 <= d; e += 4) {
                int j0 = bucket[start + e + 0];
                int j1 = bucket[start + e + 1];
                int j2 = bucket[start + e + 2];
                int j3 = bucket[start + e + 3];
                float v0 = x[(size_t)j0 * DIM + lane];
                float v1 = x[(size_t)j1 * DIM + lane];
                float v2 = x[(size_t)j2 * DIM + lane];
                float v3 = x[(size_t)j3 * DIM + lane];
                sum += (v0 + v1) + (v2 + v3);
            }
            for (; e < d; ++e) {
                int j = bucket[start + e];
                sum += x[(size_t)j * DIM + lane];
            }
            float inv = (d > 0) ? 1.0f / (float)d : 0.0f;
            sum *= inv;
        }
        tile[row * PAD + lane] = sum;    // addr = row*65 + lane: conflict-free
    }
    __syncthreads();

    // ---- matmul: acc[q] = sum_k agg[nd][k] * W[d0+q][k] ----
    const int nd  = threadIdx.x & 63;
    const int d0u = __builtin_amdgcn_readfirstlane((threadIdx.x >> 6) << 4);
    const float* __restrict__ Wr = W + (size_t)d0u * DIM;   // uniform base -> s_load

    float acc[16];
#pragma unroll
    for (int q = 0; q < 16; ++q) acc[q] = 0.0f;

#pragma unroll 4
    for (int k = 0; k < DIM; ++k) {
        float a = tile[nd * PAD + k];    // lane*65+k: conflict-free
#pragma unroll
        for (int q = 0; q < 16; ++q)
            acc[q] = fmaf(a, Wr[(size_t)q * DIM + k], acc[q]);
    }

    // ---- epilogue: mask + bias, round-trip LDS for coalesced store ----
    int gnode = base + nd;
    int dg = (gnode < N_NODES) ? deg[gnode] : 0;
    __syncthreads();                     // everyone done reading agg
#pragma unroll
    for (int q = 0; q < 16; ++q) {
        float v = (dg > 0) ? (acc[q] + b[d0u + q]) : 0.0f;
        tile[nd * PAD + d0u + q] = v;    // lane*65 + const: conflict-free
    }
    __syncthreads();

#pragma unroll
    for (int r = 0; r < 16; ++r) {
        int idx = r * 256 + threadIdx.x;           // 0..4095
        int row = idx >> 6, d = idx & 63;
        int g = base + row;
        if (g < N_NODES)
            out[(size_t)g * DIM + d] = tile[row * PAD + d];
    }
}

extern "C" void kernel_launch(void* const* d_in, const int* in_sizes, int n_in,
                              void* d_out, int out_size, void* d_ws, size_t ws_size,
                              hipStream_t stream) {
    const float* x  = (const float*)d_in[0];   // (N, 64)
    const int*   ei = (const int*)d_in[1];     // (2, E): [0,E) targets, [E,2E) sources
    const float* W  = (const float*)d_in[2];   // (64, 64)
    const float* b  = (const float*)d_in[3];   // (64,)
    float* out = (float*)d_out;                // (N, 64)

    // Workspace layout (~8.8 MB)
    int* deg    = (int*)d_ws;            // N
    int* offs   = deg + N_NODES;         // N
    int* ticket = offs + N_NODES;        // E
    int* bucket = ticket + N_EDGES;      // E
    int* bsums  = bucket + N_EDGES;      // 256

    // Only deg needs zeroing (everything else is fully overwritten each call).
    hipMemsetAsync(deg, 0, N_NODES * sizeof(int), stream);

    count_ticket<<<(N_EDGES + 255) / 256, 256, 0, stream>>>(ei, deg, ticket);
    scan_block<<<NBLK, SCAN_BLK, 0, stream>>>(deg, offs, bsums);
    scan_sums<<<1, 256, 0, stream>>>(bsums);
    add_base<<<NBLK, SCAN_BLK, 0, stream>>>(offs, bsums);
    scatter_kernel<<<(N_EDGES + 255) / 256, 256, 0, stream>>>(ei, offs, ticket, bucket);
    fused_gather_mm<<<(N_NODES + TILE - 1) / TILE, 256, 0, stream>>>(
        x, offs, deg, bucket, W, b, out);
}